// Round 2
// baseline (1793.408 us; speedup 1.0000x reference)
//
#include <hip/hip_runtime.h>

constexpr int CIN  = 32;
constexpr int COUT = 64;
constexpr int TT   = 128;
constexpr int NN   = 512;
constexpr int THREADS = 512;

// Swizzled LDS layout for [512][32] fp32 tiles: element (n, c) chunk cj=c>>2 lives at
// float index (n<<5) | (((cj ^ n) & 7) << 2) | (c&3).  16B-aligned; for b128 ops each
// 8-lane phase group hits 8 distinct 16B slots spanning all 32 banks -> conflict-free
// for per-lane-row access; broadcast reads are conflict-free by definition.
__device__ __forceinline__ int swzbase(int n) {
    return (n << 5) | ((n & 7) << 2);
}

// a0[c] = sum_i g0[i] * src[i][c]   (src = swizzled LDS tile; reads are wave-uniform broadcasts)
__device__ __forceinline__ void gemv_row(
    const float* __restrict__ src,
    const float* __restrict__ g0p,
    float (&a0)[32])
{
    #pragma unroll
    for (int c = 0; c < 32; ++c) a0[c] = 0.0f;
    for (int i = 0; i < NN; i += 4) {
        const float4 ga = *(const float4*)&g0p[i];
        const float gav[4] = {ga.x, ga.y, ga.z, ga.w};
        #pragma unroll
        for (int u = 0; u < 4; ++u) {
            const int sb = swzbase(i + u);
            const float g0 = gav[u];
            #pragma unroll
            for (int j = 0; j < 8; ++j) {
                const float4 xv = *(const float4*)&src[sb ^ (j << 2)];
                a0[4*j+0] = fmaf(g0, xv.x, a0[4*j+0]);
                a0[4*j+1] = fmaf(g0, xv.y, a0[4*j+1]);
                a0[4*j+2] = fmaf(g0, xv.z, a0[4*j+2]);
                a0[4*j+3] = fmaf(g0, xv.w, a0[4*j+3]);
            }
        }
    }
}

// Channel mix + bias + residual + store for one node n.
// gc[n][j] = bias[j] + sum_i X0[n][i]*(W0-W2)[i][j] + Y1[n][i]*W1[i][j] + Z[n][i]*(2W2)[i][j]
// out[..j..] = gc + (j<32 ? X0[n][j] : 0)
__device__ __forceinline__ void mix_and_store(
    const int n, const float* __restrict__ sX, const float* __restrict__ sY,
    const float* __restrict__ sW, const float* __restrict__ sB,
    const float (&zz)[32], float* __restrict__ outp)
{
    const int sb = swzbase(n);
    float xa[32], ya[32];
    #pragma unroll
    for (int j = 0; j < 8; ++j) {
        const float4 xv = *(const float4*)&sX[sb ^ (j << 2)];
        const float4 yv = *(const float4*)&sY[sb ^ (j << 2)];
        xa[4*j+0] = xv.x; xa[4*j+1] = xv.y; xa[4*j+2] = xv.z; xa[4*j+3] = xv.w;
        ya[4*j+0] = yv.x; ya[4*j+1] = yv.y; ya[4*j+2] = yv.z; ya[4*j+3] = yv.w;
    }
    #pragma unroll 2
    for (int jj = 0; jj < 16; ++jj) {
        float4 acc = *(const float4*)&sB[4*jj];
        #pragma unroll
        for (int i = 0; i < 32; ++i) {
            const float4 w0 = *(const float4*)&sW[i*64 + 4*jj];              // W0 - W2
            const float4 w1 = *(const float4*)&sW[2048 + i*64 + 4*jj];       // W1
            const float4 w2 = *(const float4*)&sW[4096 + i*64 + 4*jj];       // 2*W2
            acc.x = fmaf(xa[i], w0.x, fmaf(ya[i], w1.x, fmaf(zz[i], w2.x, acc.x)));
            acc.y = fmaf(xa[i], w0.y, fmaf(ya[i], w1.y, fmaf(zz[i], w2.y, acc.y)));
            acc.z = fmaf(xa[i], w0.z, fmaf(ya[i], w1.z, fmaf(zz[i], w2.z, acc.z)));
            acc.w = fmaf(xa[i], w0.w, fmaf(ya[i], w1.w, fmaf(zz[i], w2.w, acc.w)));
        }
        if (jj < 8) {  // residual x_in for output channels j<32 == X0[n][j]
            const float4 res = *(const float4*)&sX[sb ^ (jj << 2)];
            acc.x += res.x; acc.y += res.y; acc.z += res.z; acc.w += res.w;
        }
        float* o = outp + (size_t)(4*jj) * (TT*NN);
        o[0]                   = acc.x;
        o[(size_t)(TT*NN)]     = acc.y;
        o[(size_t)(2*TT*NN)]   = acc.z;
        o[(size_t)(3*TT*NN)]   = acc.w;
    }
}

__global__ __launch_bounds__(THREADS, 2)
void cheb_fused(const float* __restrict__ x, const float* __restrict__ gso,
                const float* __restrict__ w, const float* __restrict__ bias,
                float* __restrict__ out)
{
    __shared__ __align__(16) float sX[NN * 32];           // 64 KiB  X0 (swizzled)
    __shared__ __align__(16) float sY[NN * 32];           // 64 KiB  Y1 (swizzled)
    __shared__ __align__(16) float sW[3 * CIN * COUT];    // 24 KiB  {W0-W2, W1, 2W2}[i<32][j]
    __shared__ __align__(16) float sB[COUT];

    const int bt  = blockIdx.x;          // 0..2047
    const int b   = bt >> 7;
    const int t   = bt & (TT - 1);
    const int tid = threadIdx.x;         // 0..511 == node index

    // ---- stage combined weights ----
    for (int idx = tid; idx < 3 * CIN * COUT; idx += THREADS) {
        const int k = idx >> 11;          // / (CIN*COUT)
        const int r = idx & 2047;
        const int i = r >> 6;
        const int j = r & 63;
        const float wv = w[k * (COUT*COUT) + i * COUT + j];
        float v;
        if (k == 0)      v = wv - w[2 * (COUT*COUT) + i * COUT + j];
        else if (k == 1) v = wv;
        else             v = 2.0f * wv;
        sW[idx] = v;
    }
    if (tid < COUT) sB[tid] = bias[tid];

    // ---- load X0 = xp[b,t,:, :32] into LDS (coalesced: lane = node) ----
    const size_t x_bt = (size_t)b * (CIN * TT * NN) + (size_t)t * NN;   // &x[b][0][t][0]
    {
        float v0[32];
        #pragma unroll
        for (int c = 0; c < 32; ++c) {
            v0[c] = x[x_bt + (size_t)c * (TT * NN) + tid];
        }
        const int sb0 = swzbase(tid);
        #pragma unroll
        for (int j = 0; j < 8; ++j) {
            *(float4*)&sX[sb0 ^ (j << 2)] = make_float4(v0[4*j], v0[4*j+1], v0[4*j+2], v0[4*j+3]);
        }
    }
    __syncthreads();

    // ---- Y1 = GSO @ X0 (each thread: 1 row) ----
    const float* g0p = gso + (size_t)tid * NN;
    {
        float y0[32];
        gemv_row(sX, g0p, y0);
        const int sb0 = swzbase(tid);
        #pragma unroll
        for (int j = 0; j < 8; ++j) {
            *(float4*)&sY[sb0 ^ (j << 2)] = make_float4(y0[4*j], y0[4*j+1], y0[4*j+2], y0[4*j+3]);
        }
    }
    __syncthreads();

    // ---- Z = GSO @ Y1, then channel-mix + residual + store ----
    float z0[32];
    gemv_row(sY, g0p, z0);

    float* outp0 = out + (size_t)b * ((size_t)COUT * TT * NN) + (size_t)t * NN;
    mix_and_store(tid, sX, sY, sW, sB, z0, outp0 + tid);
}

extern "C" void kernel_launch(void* const* d_in, const int* in_sizes, int n_in,
                              void* d_out, int out_size, void* d_ws, size_t ws_size,
                              hipStream_t stream) {
    const float* x    = (const float*)d_in[0];
    const float* gso  = (const float*)d_in[1];
    const float* w    = (const float*)d_in[2];
    const float* bias = (const float*)d_in[3];
    float* out        = (float*)d_out;

    cheb_fused<<<dim3(16 * 128), dim3(THREADS), 0, stream>>>(x, gso, w, bias, out);
}

// Round 3
// 855.071 us; speedup vs baseline: 2.0974x; 2.0974x over previous
//
#include <hip/hip_runtime.h>

typedef short  s16x8 __attribute__((ext_vector_type(8)));   // 8 bf16 (MFMA A/B frag)
typedef ushort u16x4 __attribute__((ext_vector_type(4)));
typedef float  f32x4 __attribute__((ext_vector_type(4)));   // MFMA C/D frag

constexpr int CIN = 32, COUT = 64, TT = 128, NN = 512;
constexpr int THREADS = 512;

__device__ __forceinline__ ushort f2bf(float f) {            // RNE float->bf16
    union { float f; unsigned u; } v; v.f = f;
    return (ushort)((v.u + 0x7FFFu + ((v.u >> 16) & 1u)) >> 16);
}
__device__ __forceinline__ float bf2f(ushort h) {
    union { unsigned u; float f; } v; v.u = ((unsigned)h) << 16; return v.f;
}

// G -> bf16 hi/lo split (hi + lo recovers ~17 mantissa bits)
__global__ void prep_gso(const float* __restrict__ g,
                         ushort* __restrict__ ghi, ushort* __restrict__ glo) {
    const int i = blockIdx.x * 256 + threadIdx.x;            // 512*512 elements
    const float v = g[i];
    const ushort hi = f2bf(v);
    ghi[i] = hi;
    glo[i] = f2bf(v - bf2f(hi));
}

// ---- swizzled LDS layouts (ushort units), both <=2-way bank aliasing ----
// _T: [32 ch][512 n]  (K=n contiguous; B-frag source for the G GEMMs)
__device__ __forceinline__ int idxT(int c, int n) {
    return c * 512 + ((((n >> 3) ^ (c & 7)) << 3) | (n & 7));
}
// _N: [512 n][32 ch]  (K=ch contiguous; A-frag source for the mix GEMM)
__device__ __forceinline__ int idxN(int n, int c) {
    return n * 32 + ((((c >> 3) ^ ((n >> 1) & 3)) << 3) | (c & 7));
}

__global__ __launch_bounds__(THREADS, 2)
void cheb_mfma(const float* __restrict__ x, const ushort* __restrict__ ghi,
               const ushort* __restrict__ glo, const float* __restrict__ wt,
               const float* __restrict__ bias, float* __restrict__ out)
{
    __shared__ ushort sXT[32 * 512];    // 32 KiB
    __shared__ ushort sYT[32 * 512];    // 32 KiB
    __shared__ ushort sXN[512 * 32];    // 32 KiB
    __shared__ ushort sYN[512 * 32];    // 32 KiB
    __shared__ ushort sW [3 * 64 * 32]; // 12 KiB   Wt_s[j][i] = W'_s[i][j] bf16
    ushort* sZN = sXT;                  // X_T dead after GEMM1 -> reuse for Z_N

    const int tid = threadIdx.x;
    const int wv  = tid >> 6;          // wave 0..7  (owns rows wv*64..wv*64+63)
    const int l   = tid & 63;
    const int lr  = l & 15;            // row (A) / col (B,D) within 16x16 tile
    const int lk  = l >> 4;            // k-chunk 0..3 (8 elems each)
    const int bt  = blockIdx.x, b = bt >> 7, t = bt & (TT - 1);

    const float* xb = x + (size_t)b * (CIN * TT * NN) + t * NN;  // xb[c*TT*NN + n]

    // ---- stage combined weights, transposed + swizzled ----
    for (int idx = tid; idx < 3 * 32 * 64; idx += THREADS) {
        const int j = idx & 63;
        const int r = idx >> 6;        // 0..95
        const int i = r & 31;
        const int s = r >> 5;          // 0..2
        const float w0 = wt[0 * 4096 + i * 64 + j];
        const float w1 = wt[1 * 4096 + i * 64 + j];
        const float w2 = wt[2 * 4096 + i * 64 + j];
        const float v  = (s == 0) ? (w0 - w2) : (s == 1) ? w1 : 2.0f * w2;
        sW[s * 2048 + j * 32 + ((((i >> 3) ^ ((j >> 1) & 3)) << 3) | (i & 7))] = f2bf(v);
    }

    // ---- stage X0: thread n loads 32 channels (coalesced), writes both layouts ----
    {
        const int n = tid;
        ushort xh[32];
        #pragma unroll
        for (int c = 0; c < 32; ++c) xh[c] = f2bf(xb[c * (TT * NN) + n]);
        #pragma unroll
        for (int c = 0; c < 32; ++c) sXT[idxT(c, n)] = xh[c];
        #pragma unroll
        for (int q = 0; q < 4; ++q) {
            s16x8 pk;
            #pragma unroll
            for (int e = 0; e < 8; ++e) pk[e] = (short)xh[q * 8 + e];
            *(s16x8*)&sXN[n * 32 + ((q ^ ((n >> 1) & 3)) << 3)] = pk;
        }
    }
    __syncthreads();

    // ---- GEMM over G (split hi/lo A): acc[m][nt] += G[rows][k] * Bsrc[k][cols] ----
    auto run_gemm = [&](const ushort* __restrict__ Bsrc, f32x4 (&acc)[4][2]) {
        const f32x4 zz = {0.f, 0.f, 0.f, 0.f};
        #pragma unroll
        for (int m = 0; m < 4; ++m)
            #pragma unroll
            for (int nt = 0; nt < 2; ++nt) acc[m][nt] = zz;
        #pragma unroll 4
        for (int kk = 0; kk < 16; ++kk) {
            const int k0 = kk * 32 + lk * 8;
            s16x8 bfr[2];
            #pragma unroll
            for (int nt = 0; nt < 2; ++nt) {
                const int c = nt * 16 + lr;
                bfr[nt] = *(const s16x8*)&Bsrc[c * 512 + (((k0 >> 3) ^ (c & 7)) << 3)];
            }
            #pragma unroll
            for (int m = 0; m < 4; ++m) {
                const int row = wv * 64 + m * 16 + lr;
                const s16x8 ah = *(const s16x8*)(ghi + row * 512 + k0);
                const s16x8 al = *(const s16x8*)(glo + row * 512 + k0);
                #pragma unroll
                for (int nt = 0; nt < 2; ++nt) {
                    acc[m][nt] = __builtin_amdgcn_mfma_f32_16x16x32_bf16(ah, bfr[nt], acc[m][nt], 0, 0, 0);
                    acc[m][nt] = __builtin_amdgcn_mfma_f32_16x16x32_bf16(al, bfr[nt], acc[m][nt], 0, 0, 0);
                }
            }
        }
    };

    // ---- GEMM1: Y1 = G @ X0 ----
    {
        f32x4 a1[4][2];
        run_gemm(sXT, a1);
        // D layout: col = lr (+16*nt), rows = lk*4 + reg  (m89-verified)
        #pragma unroll
        for (int m = 0; m < 4; ++m) {
            const int h0 = wv * 64 + m * 16 + lk * 4;
            #pragma unroll
            for (int nt = 0; nt < 2; ++nt) {
                const int c = nt * 16 + lr;
                u16x4 pv;
                #pragma unroll
                for (int r = 0; r < 4; ++r) pv[r] = f2bf(a1[m][nt][r]);
                *(u16x4*)&sYT[c * 512 + ((((h0 >> 3) ^ (c & 7)) << 3) | (h0 & 7))] = pv;
                #pragma unroll
                for (int r = 0; r < 4; ++r) sYN[idxN(h0 + r, c)] = pv[r];
            }
        }
    }
    __syncthreads();

    // ---- GEMM2: Z = G @ Y1 ----
    {
        f32x4 a2[4][2];
        run_gemm(sYT, a2);
        #pragma unroll
        for (int m = 0; m < 4; ++m) {
            const int h0 = wv * 64 + m * 16 + lk * 4;
            #pragma unroll
            for (int nt = 0; nt < 2; ++nt) {
                const int c = nt * 16 + lr;
                #pragma unroll
                for (int r = 0; r < 4; ++r) sZN[idxN(h0 + r, c)] = f2bf(a2[m][nt][r]);
            }
        }
    }
    __syncthreads();

    // ---- mix GEMM: gc = [X0|Y1|Z] (512x96) @ Wcat (96x64) ----
    f32x4 mac[4][4];
    {
        const f32x4 zz = {0.f, 0.f, 0.f, 0.f};
        #pragma unroll
        for (int m = 0; m < 4; ++m)
            #pragma unroll
            for (int nt = 0; nt < 4; ++nt) mac[m][nt] = zz;
        const ushort* __restrict__ As[3] = {sXN, sYN, sZN};
        #pragma unroll
        for (int s = 0; s < 3; ++s) {
            s16x8 bw[4];
            #pragma unroll
            for (int nt = 0; nt < 4; ++nt) {
                const int j = nt * 16 + lr;
                bw[nt] = *(const s16x8*)&sW[s * 2048 + j * 32 + ((lk ^ ((j >> 1) & 3)) << 3)];
            }
            #pragma unroll
            for (int m = 0; m < 4; ++m) {
                const int n = wv * 64 + m * 16 + lr;
                const s16x8 av = *(const s16x8*)&As[s][n * 32 + ((lk ^ ((n >> 1) & 3)) << 3)];
                #pragma unroll
                for (int nt = 0; nt < 4; ++nt)
                    mac[m][nt] = __builtin_amdgcn_mfma_f32_16x16x32_bf16(av, bw[nt], mac[m][nt], 0, 0, 0);
            }
        }
    }

    // ---- epilogue: + bias + residual (fp32 from global, exact), store ----
    float* ob = out + (size_t)b * ((size_t)COUT * TT * NN) + t * NN;
    #pragma unroll
    for (int nt = 0; nt < 4; ++nt) {
        const int j = nt * 16 + lr;
        const float bj = bias[j];
        #pragma unroll
        for (int m = 0; m < 4; ++m) {
            const int n0 = wv * 64 + m * 16 + lk * 4;
            f32x4 v = mac[m][nt];
            v[0] += bj; v[1] += bj; v[2] += bj; v[3] += bj;
            if (nt < 2) {   // residual x_in for output channels j<32
                const float4 rx = *(const float4*)&xb[j * (TT * NN) + n0];
                v[0] += rx.x; v[1] += rx.y; v[2] += rx.z; v[3] += rx.w;
            }
            *(float4*)&ob[(size_t)j * (TT * NN) + n0] = make_float4(v[0], v[1], v[2], v[3]);
        }
    }
}

extern "C" void kernel_launch(void* const* d_in, const int* in_sizes, int n_in,
                              void* d_out, int out_size, void* d_ws, size_t ws_size,
                              hipStream_t stream) {
    const float* x    = (const float*)d_in[0];
    const float* gso  = (const float*)d_in[1];
    const float* wt   = (const float*)d_in[2];
    const float* bias = (const float*)d_in[3];
    float* out        = (float*)d_out;

    ushort* ghi = (ushort*)d_ws;            // 512 KiB
    ushort* glo = ghi + 512 * 512;          // 512 KiB

    prep_gso<<<dim3(1024), dim3(256), 0, stream>>>(gso, ghi, glo);
    cheb_mfma<<<dim3(16 * 128), dim3(THREADS), 0, stream>>>(x, ghi, glo, wt, bias, out);
}